// Round 1
// 1461.069 us; speedup vs baseline: 1.0867x; 1.0867x over previous
//
#include <hip/hip_runtime.h>
#include <hip/hip_bf16.h>
#include <string.h>

#define NB 8
#define LSEQ 4096
#define DMOD 1024
#define NCH (NB * DMOD)   // 8192 channels (b, c=h*128+dk)
#define TOPK 16

typedef unsigned short u16;
typedef unsigned int u32;
typedef __attribute__((ext_vector_type(4))) float f32x4;
typedef __attribute__((ext_vector_type(8))) _Float16 f16x8;

__device__ __forceinline__ float h2f(u16 u) {
  _Float16 h;
  __builtin_memcpy(&h, &u, 2);
  return (float)h;
}
__device__ __forceinline__ u16 f2h(float f) {
  _Float16 h = (_Float16)f;  // v_cvt_f16_f32, RNE
  u16 u;
  __builtin_memcpy(&u, &h, 2);
  return u;
}
__device__ __forceinline__ u32 pk2(float a, float b) {
  return (u32)f2h(a) | ((u32)f2h(b) << 16);
}
__device__ __forceinline__ float2 cmul(float2 a, float2 b) {
  return make_float2(a.x * b.x - a.y * b.y, a.x * b.y + a.y * b.x);
}
__device__ __forceinline__ float2 cmul_conj(float2 a, float2 b) {  // a * conj(b)
  return make_float2(a.x * b.x + a.y * b.y, a.y * b.x - a.x * b.y);
}

// ---------------- twiddle table: T[x] = exp(-2*pi*i*x/4096), x<4096 ----------
__global__ __launch_bounds__(256) void twiddle_k(float2* tw) {
  int i = blockIdx.x * 256 + threadIdx.x;
  if (i < 4096) {
    float ang = -2.0f * 3.14159265358979323846f * (float)i / 4096.0f;
    tw[i] = make_float2(cosf(ang), sinf(ang));
  }
}

// -------- weight transpose + fp16 downcast: dst[c][r] = fp16(src[r][c]) -----
__global__ __launch_bounds__(256) void transpose_w_k(const float* __restrict__ src,
                                                     u16* __restrict__ dst,
                                                     int R, int C) {
  __shared__ u16 tile[64][66];
  int c0 = blockIdx.x * 64, r0 = blockIdx.y * 64;
  int tx = threadIdx.x & 63, ty = threadIdx.x >> 6;
#pragma unroll
  for (int i = 0; i < 16; i++) {
    int r = ty + i * 4;
    tile[r][tx] = f2h(src[(size_t)(r0 + r) * C + c0 + tx]);
  }
  __syncthreads();
#pragma unroll
  for (int i = 0; i < 16; i++) {
    int cc = ty + i * 4;
    dst[(size_t)(c0 + cc) * R + r0 + tx] = tile[tx][cc];
  }
}

// ------- proj GEMM: out[b][n][t] = fp16( sum_k A[m][k]*Btw[n][k] + bias[n] )
// A fp32 [M=32768][K=1024] (m = b*4096+t), Btw fp16 [N=1024][K], bias fp32.
__global__ __launch_bounds__(256) void gemm_proj_k(const float* __restrict__ A,
                                                   const u16* __restrict__ Btw,
                                                   const float* __restrict__ bias,
                                                   u16* __restrict__ out,
                                                   int K) {
  __shared__ __align__(16) u16 smem[17408];  // staging (2x128x40) / C-tile (128x136)
  u16* As = smem;
  u16* Bs = smem + 5120;
  int tid = threadIdx.x;
  int lane = tid & 63, wave = tid >> 6;
  int quad = lane >> 4, l15 = lane & 15;
  int m0 = blockIdx.y * 128, n0 = blockIdx.x * 128;
  int wm = (wave >> 1) * 64, wn = (wave & 1) * 64;
  int r_a = tid >> 2, kc = (tid & 3) * 8;

  f32x4 acc[4][4];
#pragma unroll
  for (int i = 0; i < 4; i++)
#pragma unroll
    for (int j = 0; j < 4; j++)
      acc[i][j] = (f32x4){0.f, 0.f, 0.f, 0.f};

  for (int kk = 0; kk < K; kk += 32) {
    __syncthreads();
    const float* ga0 = A + (size_t)(m0 + r_a) * K + kk + kc;
    const float* ga1 = ga0 + (size_t)64 * K;
    float4 x0 = *(const float4*)ga0;
    float4 x1 = *(const float4*)(ga0 + 4);
    float4 y0 = *(const float4*)ga1;
    float4 y1 = *(const float4*)(ga1 + 4);
    uint4 wa, wb;
    wa.x = pk2(x0.x, x0.y); wa.y = pk2(x0.z, x0.w);
    wa.z = pk2(x1.x, x1.y); wa.w = pk2(x1.z, x1.w);
    wb.x = pk2(y0.x, y0.y); wb.y = pk2(y0.z, y0.w);
    wb.z = pk2(y1.x, y1.y); wb.w = pk2(y1.z, y1.w);
    *(uint4*)&As[r_a * 40 + kc] = wa;
    *(uint4*)&As[(r_a + 64) * 40 + kc] = wb;
    const u16* gb = Btw + (size_t)(n0 + r_a) * K + kk + kc;
    *(uint4*)&Bs[r_a * 40 + kc] = *(const uint4*)gb;
    *(uint4*)&Bs[(r_a + 64) * 40 + kc] = *(const uint4*)(gb + (size_t)64 * K);
    __syncthreads();
    f16x8 af[4], bfr[4];
    int ka = quad * 8;
#pragma unroll
    for (int i = 0; i < 4; i++)
      af[i] = *(const f16x8*)&As[(wm + i * 16 + l15) * 40 + ka];
#pragma unroll
    for (int j = 0; j < 4; j++)
      bfr[j] = *(const f16x8*)&Bs[(wn + j * 16 + l15) * 40 + ka];
#pragma unroll
    for (int i = 0; i < 4; i++)
#pragma unroll
      for (int j = 0; j < 4; j++)
        acc[i][j] = __builtin_amdgcn_mfma_f32_16x16x32_f16(af[i], bfr[j], acc[i][j], 0, 0, 0);
  }

  __syncthreads();
  float bv[4];
#pragma unroll
  for (int j = 0; j < 4; j++) bv[j] = bias[n0 + wn + j * 16 + l15];
  u16* Ct = smem;  // [n 128][m 136] transposed C-tile
#pragma unroll
  for (int i = 0; i < 4; i++) {
#pragma unroll
    for (int j = 0; j < 4; j++) {
      int ml = wm + i * 16 + quad * 4;
      int nl = wn + j * 16 + l15;
      unsigned long long pkv = 0;
#pragma unroll
      for (int r = 0; r < 4; r++)
        pkv |= ((unsigned long long)f2h(acc[i][j][r] + bv[j])) << (16 * r);
      *(unsigned long long*)&Ct[nl * 136 + ml] = pkv;
    }
  }
  __syncthreads();
  int b_ = m0 >> 12, t0 = m0 & 4095;
#pragma unroll
  for (int it = 0; it < 8; it++) {
    int row = (tid >> 4) + it * 16;
    int col = (tid & 15) * 8;
    uint4 v = *(const uint4*)&Ct[row * 136 + col];
    *(uint4*)(out + (size_t)b_ * DMOD * LSEQ + (size_t)(n0 + row) * LSEQ + t0 + col) = v;
  }
}

// ------- final GEMM: out[b][t][n] = fp32( sum_c Acm[b][c][t]*Wot[n][c] ) + bo
// Acm fp16 channel-major [B][1024][4096]; A transposed during staging.
__global__ __launch_bounds__(256) void gemm_tA_k(const u16* __restrict__ Acm,
                                                 const u16* __restrict__ Wot,
                                                 const float* __restrict__ bias,
                                                 float* __restrict__ out) {
  __shared__ __align__(16) u16 smem[17408];
  u32* Ta = (u32*)smem;            // 16 c-pairs x 132 dwords = 2112 dw (8448 B)
  u16* Bs = smem + 4224;           // 128 x 40
  int tid = threadIdx.x;
  int lane = tid & 63, wave = tid >> 6;
  int quad = lane >> 4, l15 = lane & 15;
  int b = blockIdx.z;
  int m0 = blockIdx.y * 128, n0 = blockIdx.x * 128;
  int wm = (wave >> 1) * 64, wn = (wave & 1) * 64;
  int cp = tid >> 4, t0s = (tid & 15) * 8;   // A staging: c-pair, t-offset
  int r_b = tid >> 2, kc = (tid & 3) * 8;    // B staging
  const u16* Ab = Acm + (size_t)b * DMOD * LSEQ;

  f32x4 acc[4][4];
#pragma unroll
  for (int i = 0; i < 4; i++)
#pragma unroll
    for (int j = 0; j < 4; j++)
      acc[i][j] = (f32x4){0.f, 0.f, 0.f, 0.f};

  for (int kk = 0; kk < DMOD; kk += 32) {
    __syncthreads();
    const u16* ga = Ab + (size_t)(kk + 2 * cp) * LSEQ + m0 + t0s;
    uint4 v0 = *(const uint4*)ga;
    uint4 v1 = *(const uint4*)(ga + LSEQ);
    int tb = cp * 132 + t0s;
    uint4 w0, w1;
    w0.x = (v0.x & 0xffffu) | (v1.x << 16);
    w0.y = (v0.x >> 16) | (v1.x & 0xffff0000u);
    w0.z = (v0.y & 0xffffu) | (v1.y << 16);
    w0.w = (v0.y >> 16) | (v1.y & 0xffff0000u);
    w1.x = (v0.z & 0xffffu) | (v1.z << 16);
    w1.y = (v0.z >> 16) | (v1.z & 0xffff0000u);
    w1.z = (v0.w & 0xffffu) | (v1.w << 16);
    w1.w = (v0.w >> 16) | (v1.w & 0xffff0000u);
    *(uint4*)&Ta[tb] = w0;
    *(uint4*)&Ta[tb + 4] = w1;
    const u16* gb = Wot + (size_t)(n0 + r_b) * DMOD + kk + kc;
    *(uint4*)&Bs[r_b * 40 + kc] = *(const uint4*)gb;
    *(uint4*)&Bs[(r_b + 64) * 40 + kc] = *(const uint4*)(gb + (size_t)64 * DMOD);
    __syncthreads();
    f16x8 af[4], bfr[4];
    int ka = quad * 8;
#pragma unroll
    for (int i = 0; i < 4; i++) {
      int mrow = wm + i * 16 + l15;
      uint4 fa;
      fa.x = Ta[(quad * 4 + 0) * 132 + mrow];
      fa.y = Ta[(quad * 4 + 1) * 132 + mrow];
      fa.z = Ta[(quad * 4 + 2) * 132 + mrow];
      fa.w = Ta[(quad * 4 + 3) * 132 + mrow];
      af[i] = *(f16x8*)&fa;
    }
#pragma unroll
    for (int j = 0; j < 4; j++)
      bfr[j] = *(const f16x8*)&Bs[(wn + j * 16 + l15) * 40 + ka];
#pragma unroll
    for (int i = 0; i < 4; i++)
#pragma unroll
      for (int j = 0; j < 4; j++)
        acc[i][j] = __builtin_amdgcn_mfma_f32_16x16x32_f16(af[i], bfr[j], acc[i][j], 0, 0, 0);
  }

  float bv[4];
#pragma unroll
  for (int j = 0; j < 4; j++) bv[j] = bias[n0 + wn + j * 16 + l15];
  // fp32 epilogue in two 64-row passes through LDS (64 x 132 floats = 33792 B)
  float* Cf = (float*)smem;
#pragma unroll
  for (int half = 0; half < 2; half++) {
    __syncthreads();
    if ((wave >> 1) == half) {
#pragma unroll
      for (int i = 0; i < 4; i++) {
#pragma unroll
        for (int j = 0; j < 4; j++) {
          int mlocal = i * 16 + quad * 4;
          int nl = wn + j * 16 + l15;
#pragma unroll
          for (int r = 0; r < 4; r++)
            Cf[(mlocal + r) * 132 + nl] = acc[i][j][r] + bv[j];
        }
      }
    }
    __syncthreads();
#pragma unroll
    for (int it = 0; it < 8; it++) {
      int row = (tid >> 5) + it * 8;
      int col = (tid & 31) * 4;
      float4 v = *(const float4*)&Cf[row * 132 + col];
      *(float4*)(out + (size_t)b * LSEQ * DMOD +
                 (size_t)(m0 + half * 64 + row) * DMOD + n0 + col) = v;
    }
  }
}

// ---------------- per-channel FFT corr + top-16 + softmax --------------------
// Radix-16 Stockham (3 stages), one 32KB in-place LDS buffer, XOR bank swizzle.
// Stockham radix-R stage (matches proven radix-2 convention):
//   j = idx/m, k = idx%m:
//   dst[R*j*m + k + u*m] = (sum_r src[idx + r*N/R] * W_R^{ur}) * W_N^{u*j*m}
#define SWZ(t) ((t) ^ (((t) >> 4) & 15))

template <bool INV>
__device__ __forceinline__ void dft16(float2* z) {
  const float SQ = 0.70710678118654752440f;
  const float C1 = 0.92387953251128675613f;
  const float S1 = 0.38268343236508977173f;
  const float sg = INV ? 1.0f : -1.0f;
  // len=2
#pragma unroll
  for (int i = 0; i < 16; i += 2) {
    float2 a = z[i], b = z[i + 1];
    z[i] = make_float2(a.x + b.x, a.y + b.y);
    z[i + 1] = make_float2(a.x - b.x, a.y - b.y);
  }
  // len=4
  {
    const float wre[2] = {1.f, 0.f};
    const float wim[2] = {0.f, sg};
#pragma unroll
    for (int g = 0; g < 16; g += 4)
#pragma unroll
      for (int p = 0; p < 2; p++) {
        float2 a = z[g + p], b = z[g + p + 2];
        float2 t = make_float2(b.x * wre[p] - b.y * wim[p],
                               b.x * wim[p] + b.y * wre[p]);
        z[g + p] = make_float2(a.x + t.x, a.y + t.y);
        z[g + p + 2] = make_float2(a.x - t.x, a.y - t.y);
      }
  }
  // len=8
  {
    const float wre[4] = {1.f, SQ, 0.f, -SQ};
    const float wim[4] = {0.f, sg * SQ, sg, sg * SQ};
#pragma unroll
    for (int g = 0; g < 16; g += 8)
#pragma unroll
      for (int p = 0; p < 4; p++) {
        float2 a = z[g + p], b = z[g + p + 4];
        float2 t = make_float2(b.x * wre[p] - b.y * wim[p],
                               b.x * wim[p] + b.y * wre[p]);
        z[g + p] = make_float2(a.x + t.x, a.y + t.y);
        z[g + p + 4] = make_float2(a.x - t.x, a.y - t.y);
      }
  }
  // len=16
  {
    const float wre[8] = {1.f, C1, SQ, S1, 0.f, -S1, -SQ, -C1};
    const float wim[8] = {0.f, sg * S1, sg * SQ, sg * C1, sg, sg * C1, sg * SQ, sg * S1};
#pragma unroll
    for (int p = 0; p < 8; p++) {
      float2 a = z[p], b = z[p + 8];
      float2 t = make_float2(b.x * wre[p] - b.y * wim[p],
                             b.x * wim[p] + b.y * wre[p]);
      z[p] = make_float2(a.x + t.x, a.y + t.y);
      z[p + 8] = make_float2(a.x - t.x, a.y - t.y);
    }
  }
}

__global__ __launch_bounds__(256, 4) void fft_corr_topk_k(const u16* __restrict__ Qt,
                                                          const u16* __restrict__ Kt,
                                                          const float2* __restrict__ tw,
                                                          float* __restrict__ topw,
                                                          int* __restrict__ topd) {
  __shared__ float2 buf[4096];  // 32 KB, XOR-swizzled complex buffer
  __shared__ float candv[256];
  __shared__ int candi[256];
  __shared__ float tvs[TOPK];
  __shared__ int tds[TOPK];
  __shared__ int winner;
  int ch = blockIdx.x;
  int tid = threadIdx.x;
  const u16* qrow = Qt + (size_t)ch * LSEQ;
  const u16* krow = Kt + (size_t)ch * LSEQ;
  const int rev[16] = {0, 8, 4, 12, 2, 10, 6, 14, 1, 9, 5, 13, 3, 11, 7, 15};
  float2 z[16];

  // ---- forward stage 1 (m=1): global -> regs -> DFT16 -> twiddle -> LDS
#pragma unroll
  for (int r = 0; r < 16; r++) {
    int t = tid + 256 * r;
    z[rev[r]] = make_float2(h2f(qrow[t]), h2f(krow[t]));
  }
  dft16<false>(z);
#pragma unroll
  for (int u = 0; u < 16; u++) {
    float2 w = tw[(u * tid) & 4095];
    buf[SWZ(16 * tid + u)] = cmul(z[u], w);
  }
  __syncthreads();

  // ---- forward stage 2 (m=16)
  {
    int k16 = tid & 15, j = tid >> 4;
#pragma unroll
    for (int r = 0; r < 16; r++) z[rev[r]] = buf[SWZ(tid + 256 * r)];
    __syncthreads();
    dft16<false>(z);
#pragma unroll
    for (int u = 0; u < 16; u++) {
      float2 w = tw[(u * j * 16) & 4095];
      buf[SWZ(256 * j + k16 + 16 * u)] = cmul(z[u], w);
    }
  }
  __syncthreads();

  // ---- forward stage 3 (m=256, no twiddle): leaves Z[t] in buf
#pragma unroll
  for (int r = 0; r < 16; r++) z[rev[r]] = buf[SWZ(tid + 256 * r)];
  __syncthreads();
  dft16<false>(z);
#pragma unroll
  for (int u = 0; u < 16; u++) buf[SWZ(tid + 256 * u)] = z[u];
  __syncthreads();

  // ---- pointwise spectrum split + inverse stage 1 (m=1), fused
#pragma unroll
  for (int r = 0; r < 16; r++) {
    int t = tid + 256 * r;
    float2 zf = buf[SWZ(t)];
    float2 zn = buf[SWZ((4096 - t) & 4095)];
    float ax = zf.x + zn.x, ay = zf.y - zn.y;  // a = zf + conj(zn)
    float dx = zf.x - zn.x, dy = zf.y + zn.y;  // d = zf - conj(zn)
    float px = ax * dx + ay * dy;              // Re(a*conj(d))
    float py = ay * dx - ax * dy;              // Im(a*conj(d))
    z[rev[r]] = make_float2(-0.25f * py, 0.25f * px);  // (i/4)*a*conj(d)
  }
  __syncthreads();
  dft16<true>(z);
#pragma unroll
  for (int u = 0; u < 16; u++) {
    float2 w = tw[(u * tid) & 4095];
    buf[SWZ(16 * tid + u)] = cmul_conj(z[u], w);
  }
  __syncthreads();

  // ---- inverse stage 2 (m=16)
  {
    int k16 = tid & 15, j = tid >> 4;
#pragma unroll
    for (int r = 0; r < 16; r++) z[rev[r]] = buf[SWZ(tid + 256 * r)];
    __syncthreads();
    dft16<true>(z);
#pragma unroll
    for (int u = 0; u < 16; u++) {
      float2 w = tw[(u * j * 16) & 4095];
      buf[SWZ(256 * j + k16 + 16 * u)] = cmul_conj(z[u], w);
    }
  }
  __syncthreads();

  // ---- inverse stage 3 (m=256): corr values stay in registers
#pragma unroll
  for (int r = 0; r < 16; r++) z[rev[r]] = buf[SWZ(tid + 256 * r)];
  dft16<true>(z);
  float vals[16];  // vals[u] = 4096*corr[tid + 256*u]
#pragma unroll
  for (int u = 0; u < 16; u++) vals[u] = z[u].x;

  // ---- top-16 via cached per-thread local max (ties -> smaller t)
  const float NEGINF = -__builtin_inff();
  {
    float bvv = vals[0];
    int bu = 0;
#pragma unroll
    for (int u = 1; u < 16; u++)
      if (vals[u] > bvv) { bvv = vals[u]; bu = u; }
    candv[tid] = bvv;
    candi[tid] = tid + (bu << 8);
  }
  for (int r = 0; r < TOPK; r++) {
    __syncthreads();
    if (tid < 64) {
      float v0 = candv[tid];
      int i0 = candi[tid];
#pragma unroll
      for (int s2 = 1; s2 < 4; s2++) {
        float v1 = candv[tid + 64 * s2];
        int i1 = candi[tid + 64 * s2];
        if (v1 > v0 || (v1 == v0 && i1 < i0)) { v0 = v1; i0 = i1; }
      }
#pragma unroll
      for (int off = 32; off > 0; off >>= 1) {
        float ov = __shfl_down(v0, off);
        int oi = __shfl_down(i0, off);
        if (ov > v0 || (ov == v0 && oi < i0)) { v0 = ov; i0 = oi; }
      }
      if (tid == 0) { tvs[r] = v0; tds[r] = i0; winner = i0; }
    }
    __syncthreads();
    int wn = winner;
    if ((wn & 255) == tid) {
      int ku = wn >> 8;
#pragma unroll
      for (int u = 0; u < 16; u++)
        if (u == ku) vals[u] = NEGINF;  // static index keeps vals in VGPRs
      float bvv = vals[0];
      int bu = 0;
#pragma unroll
      for (int u = 1; u < 16; u++)
        if (vals[u] > bvv) { bvv = vals[u]; bu = u; }
      candv[tid] = bvv;
      candi[tid] = tid + (bu << 8);
    }
  }
  __syncthreads();
  if (tid == 0) {
    float mx = tvs[0];
    float e[TOPK];
    float s = 0.f;
    for (int k2 = 0; k2 < TOPK; k2++) {
      e[k2] = __expf((tvs[k2] - mx) * (1.0f / 4096.0f));  // /4096 undoes unnorm. iFFT
      s += e[k2];
    }
    float inv = 1.0f / s;
    for (int k2 = 0; k2 < TOPK; k2++) {
      topw[(size_t)ch * TOPK + k2] = e[k2] * inv;
      topd[(size_t)ch * TOPK + k2] = tds[k2];
    }
  }
}

// ---------------- delay aggregation: agg[c,t] = sum_k w_k * v[c,(t+d_k)%L] --
__global__ __launch_bounds__(256) void aggregate_k(const u16* __restrict__ Vt,
                                                   const float* __restrict__ topw,
                                                   const int* __restrict__ topd,
                                                   u16* __restrict__ agg) {
  __shared__ u16 vrow[4096];
  __shared__ float w_s[TOPK];
  __shared__ int d_s[TOPK];
  int ch = blockIdx.x, tid = threadIdx.x;
  const u16* src = Vt + (size_t)ch * LSEQ;
#pragma unroll
  for (int p = 0; p < 16; p++) vrow[tid + p * 256] = src[tid + p * 256];
  if (tid < TOPK) {
    w_s[tid] = topw[(size_t)ch * TOPK + tid];
    d_s[tid] = topd[(size_t)ch * TOPK + tid];
  }
  __syncthreads();
#pragma unroll
  for (int p = 0; p < 16; p++) {
    int t = tid + p * 256;
    float s = 0.f;
#pragma unroll
    for (int k = 0; k < TOPK; k++)
      s += w_s[k] * h2f(vrow[(t + d_s[k]) & 4095]);
    agg[(size_t)ch * LSEQ + t] = f2h(s);
  }
}

extern "C" void kernel_launch(void* const* d_in, const int* in_sizes, int n_in,
                              void* d_out, int out_size, void* d_ws, size_t ws_size,
                              hipStream_t stream) {
  (void)in_sizes; (void)n_in; (void)out_size; (void)ws_size;
  const float* queries = (const float*)d_in[0];
  const float* keys    = (const float*)d_in[1];
  const float* values  = (const float*)d_in[2];
  const float* Wq = (const float*)d_in[3];
  const float* bq = (const float*)d_in[4];
  const float* Wk = (const float*)d_in[5];
  const float* bk = (const float*)d_in[6];
  const float* Wv = (const float*)d_in[7];
  const float* bv = (const float*)d_in[8];
  const float* Wo = (const float*)d_in[9];
  const float* bo = (const float*)d_in[10];

  // ws layout, total ~73.1 MB (R3-proven):
  //   ws0 @ 0       : 64 MB big buffer (Qt fp16, then agg fp16)
  //   Wt's @ 64 MB  : 4 x 2 MB transposed fp16 weights
  //   tw   @ 72 MB  : 32 KB twiddles (4096 entries)
  //   topw @ 72M+64K: 512 KB, topd @ +512 KB
  char* ws = (char*)d_ws;
  u16* ws0 = (u16*)ws;
  u16* Wqt = (u16*)(ws + (64ull << 20));
  u16* Wkt = Wqt + 1024 * 1024;
  u16* Wvt = Wkt + 1024 * 1024;
  u16* Wot = Wvt + 1024 * 1024;
  float2* tw = (float2*)(ws + (72ull << 20));
  float* topw = (float*)(ws + (72ull << 20) + (64ull << 10));
  int* topd = (int*)(ws + (72ull << 20) + (64ull << 10) + (512ull << 10));

  u16* Qt = ws0;            // fp16 [B][1024][4096]
  u16* Kt = (u16*)d_out;    // fp16 K-proj in d_out (d_out is 128 MB fp32)
  u16* Vt = (u16*)d_out;    // then fp16 V-proj in d_out
  u16* agg = ws0;           // fp16 channel-major aggregation (Qt dead)

  twiddle_k<<<dim3(16), dim3(256), 0, stream>>>(tw);
  transpose_w_k<<<dim3(16, 16), dim3(256), 0, stream>>>(Wq, Wqt, 1024, 1024);
  transpose_w_k<<<dim3(16, 16), dim3(256), 0, stream>>>(Wk, Wkt, 1024, 1024);
  transpose_w_k<<<dim3(16, 16), dim3(256), 0, stream>>>(Wv, Wvt, 1024, 1024);
  transpose_w_k<<<dim3(16, 16), dim3(256), 0, stream>>>(Wo, Wot, 1024, 1024);
  dim3 gg(8, 256);
  gemm_proj_k<<<gg, dim3(256), 0, stream>>>(queries, Wqt, bq, Qt, 1024);
  gemm_proj_k<<<gg, dim3(256), 0, stream>>>(keys, Wkt, bk, Kt, 1024);
  fft_corr_topk_k<<<dim3(NCH), dim3(256), 0, stream>>>(Qt, Kt, tw, topw, topd);
  gemm_proj_k<<<gg, dim3(256), 0, stream>>>(values, Wvt, bv, Vt, 1024);
  aggregate_k<<<dim3(NCH), dim3(256), 0, stream>>>(Vt, topw, topd, agg);
  gemm_tA_k<<<dim3(8, 32, 8), dim3(256), 0, stream>>>(agg, Wot, bo, (float*)d_out);
}

// Round 2
// 1459.325 us; speedup vs baseline: 1.0880x; 1.0012x over previous
//
#include <hip/hip_runtime.h>
#include <hip/hip_bf16.h>
#include <string.h>

#define NB 8
#define LSEQ 4096
#define DMOD 1024
#define NCH (NB * DMOD)   // 8192 channels (b, c=h*128+dk)
#define TOPK 16

typedef unsigned short u16;
typedef unsigned int u32;
typedef __attribute__((ext_vector_type(4))) float f32x4;
typedef __attribute__((ext_vector_type(8))) _Float16 f16x8;

__device__ __forceinline__ float h2f(u16 u) {
  _Float16 h;
  __builtin_memcpy(&h, &u, 2);
  return (float)h;
}
__device__ __forceinline__ u16 f2h(float f) {
  _Float16 h = (_Float16)f;  // v_cvt_f16_f32, RNE
  u16 u;
  __builtin_memcpy(&u, &h, 2);
  return u;
}
__device__ __forceinline__ u32 pk2(float a, float b) {
  return (u32)f2h(a) | ((u32)f2h(b) << 16);
}
__device__ __forceinline__ float2 cmul(float2 a, float2 b) {
  return make_float2(a.x * b.x - a.y * b.y, a.x * b.y + a.y * b.x);
}
__device__ __forceinline__ float2 cmul_conj(float2 a, float2 b) {  // a * conj(b)
  return make_float2(a.x * b.x + a.y * b.y, a.y * b.x - a.x * b.y);
}

// ---------------- twiddle table: T[x] = exp(-2*pi*i*x/4096), x<4096 ----------
__global__ __launch_bounds__(256) void twiddle_k(float2* tw) {
  int i = blockIdx.x * 256 + threadIdx.x;
  if (i < 4096) {
    float ang = -2.0f * 3.14159265358979323846f * (float)i / 4096.0f;
    tw[i] = make_float2(cosf(ang), sinf(ang));
  }
}

// -------- weight transpose + fp16 downcast: dst[c][r] = fp16(src[r][c]) -----
__global__ __launch_bounds__(256) void transpose_w_k(const float* __restrict__ src,
                                                     u16* __restrict__ dst,
                                                     int R, int C) {
  __shared__ u16 tile[64][66];
  int c0 = blockIdx.x * 64, r0 = blockIdx.y * 64;
  int tx = threadIdx.x & 63, ty = threadIdx.x >> 6;
#pragma unroll
  for (int i = 0; i < 16; i++) {
    int r = ty + i * 4;
    tile[r][tx] = f2h(src[(size_t)(r0 + r) * C + c0 + tx]);
  }
  __syncthreads();
#pragma unroll
  for (int i = 0; i < 16; i++) {
    int cc = ty + i * 4;
    dst[(size_t)(c0 + cc) * R + r0 + tx] = tile[tx][cc];
  }
}

// ------- proj GEMM: out[b][n][t] = fp16( sum_k A[m][k]*Btw[n][k] + bias[n] )
// A fp32 [M=32768][K=1024] (m = b*4096+t), Btw fp16 [N=1024][K], bias fp32.
__global__ __launch_bounds__(256) void gemm_proj_k(const float* __restrict__ A,
                                                   const u16* __restrict__ Btw,
                                                   const float* __restrict__ bias,
                                                   u16* __restrict__ out,
                                                   int K) {
  __shared__ __align__(16) u16 smem[17408];  // staging (2x128x40) / C-tile (128x136)
  u16* As = smem;
  u16* Bs = smem + 5120;
  int tid = threadIdx.x;
  int lane = tid & 63, wave = tid >> 6;
  int quad = lane >> 4, l15 = lane & 15;
  int m0 = blockIdx.y * 128, n0 = blockIdx.x * 128;
  int wm = (wave >> 1) * 64, wn = (wave & 1) * 64;
  int r_a = tid >> 2, kc = (tid & 3) * 8;

  f32x4 acc[4][4];
#pragma unroll
  for (int i = 0; i < 4; i++)
#pragma unroll
    for (int j = 0; j < 4; j++)
      acc[i][j] = (f32x4){0.f, 0.f, 0.f, 0.f};

  for (int kk = 0; kk < K; kk += 32) {
    __syncthreads();
    const float* ga0 = A + (size_t)(m0 + r_a) * K + kk + kc;
    const float* ga1 = ga0 + (size_t)64 * K;
    float4 x0 = *(const float4*)ga0;
    float4 x1 = *(const float4*)(ga0 + 4);
    float4 y0 = *(const float4*)ga1;
    float4 y1 = *(const float4*)(ga1 + 4);
    uint4 wa, wb;
    wa.x = pk2(x0.x, x0.y); wa.y = pk2(x0.z, x0.w);
    wa.z = pk2(x1.x, x1.y); wa.w = pk2(x1.z, x1.w);
    wb.x = pk2(y0.x, y0.y); wb.y = pk2(y0.z, y0.w);
    wb.z = pk2(y1.x, y1.y); wb.w = pk2(y1.z, y1.w);
    *(uint4*)&As[r_a * 40 + kc] = wa;
    *(uint4*)&As[(r_a + 64) * 40 + kc] = wb;
    const u16* gb = Btw + (size_t)(n0 + r_a) * K + kk + kc;
    *(uint4*)&Bs[r_a * 40 + kc] = *(const uint4*)gb;
    *(uint4*)&Bs[(r_a + 64) * 40 + kc] = *(const uint4*)(gb + (size_t)64 * K);
    __syncthreads();
    f16x8 af[4], bfr[4];
    int ka = quad * 8;
#pragma unroll
    for (int i = 0; i < 4; i++)
      af[i] = *(const f16x8*)&As[(wm + i * 16 + l15) * 40 + ka];
#pragma unroll
    for (int j = 0; j < 4; j++)
      bfr[j] = *(const f16x8*)&Bs[(wn + j * 16 + l15) * 40 + ka];
#pragma unroll
    for (int i = 0; i < 4; i++)
#pragma unroll
      for (int j = 0; j < 4; j++)
        acc[i][j] = __builtin_amdgcn_mfma_f32_16x16x32_f16(af[i], bfr[j], acc[i][j], 0, 0, 0);
  }

  __syncthreads();
  float bv[4];
#pragma unroll
  for (int j = 0; j < 4; j++) bv[j] = bias[n0 + wn + j * 16 + l15];
  u16* Ct = smem;  // [n 128][m 136] transposed C-tile
#pragma unroll
  for (int i = 0; i < 4; i++) {
#pragma unroll
    for (int j = 0; j < 4; j++) {
      int ml = wm + i * 16 + quad * 4;
      int nl = wn + j * 16 + l15;
      unsigned long long pkv = 0;
#pragma unroll
      for (int r = 0; r < 4; r++)
        pkv |= ((unsigned long long)f2h(acc[i][j][r] + bv[j])) << (16 * r);
      *(unsigned long long*)&Ct[nl * 136 + ml] = pkv;
    }
  }
  __syncthreads();
  int b_ = m0 >> 12, t0 = m0 & 4095;
#pragma unroll
  for (int it = 0; it < 8; it++) {
    int row = (tid >> 4) + it * 16;
    int col = (tid & 15) * 8;
    uint4 v = *(const uint4*)&Ct[row * 136 + col];
    *(uint4*)(out + (size_t)b_ * DMOD * LSEQ + (size_t)(n0 + row) * LSEQ + t0 + col) = v;
  }
}

// ------- final GEMM: out[b][t][n] = fp32( sum_c Acm[b][c][t]*Wot[n][c] ) + bo
// Acm fp16 channel-major [B][1024][4096]; A transposed during staging.
__global__ __launch_bounds__(256) void gemm_tA_k(const u16* __restrict__ Acm,
                                                 const u16* __restrict__ Wot,
                                                 const float* __restrict__ bias,
                                                 float* __restrict__ out) {
  __shared__ __align__(16) u16 smem[17408];
  u32* Ta = (u32*)smem;            // 16 c-pairs x 132 dwords = 2112 dw (8448 B)
  u16* Bs = smem + 4224;           // 128 x 40
  int tid = threadIdx.x;
  int lane = tid & 63, wave = tid >> 6;
  int quad = lane >> 4, l15 = lane & 15;
  int b = blockIdx.z;
  int m0 = blockIdx.y * 128, n0 = blockIdx.x * 128;
  int wm = (wave >> 1) * 64, wn = (wave & 1) * 64;
  int cp = tid >> 4, t0s = (tid & 15) * 8;   // A staging: c-pair, t-offset
  int r_b = tid >> 2, kc = (tid & 3) * 8;    // B staging
  const u16* Ab = Acm + (size_t)b * DMOD * LSEQ;

  f32x4 acc[4][4];
#pragma unroll
  for (int i = 0; i < 4; i++)
#pragma unroll
    for (int j = 0; j < 4; j++)
      acc[i][j] = (f32x4){0.f, 0.f, 0.f, 0.f};

  for (int kk = 0; kk < DMOD; kk += 32) {
    __syncthreads();
    const u16* ga = Ab + (size_t)(kk + 2 * cp) * LSEQ + m0 + t0s;
    uint4 v0 = *(const uint4*)ga;
    uint4 v1 = *(const uint4*)(ga + LSEQ);
    int tb = cp * 132 + t0s;
    uint4 w0, w1;
    w0.x = (v0.x & 0xffffu) | (v1.x << 16);
    w0.y = (v0.x >> 16) | (v1.x & 0xffff0000u);
    w0.z = (v0.y & 0xffffu) | (v1.y << 16);
    w0.w = (v0.y >> 16) | (v1.y & 0xffff0000u);
    w1.x = (v0.z & 0xffffu) | (v1.z << 16);
    w1.y = (v0.z >> 16) | (v1.z & 0xffff0000u);
    w1.z = (v0.w & 0xffffu) | (v1.w << 16);
    w1.w = (v0.w >> 16) | (v1.w & 0xffff0000u);
    *(uint4*)&Ta[tb] = w0;
    *(uint4*)&Ta[tb + 4] = w1;
    const u16* gb = Wot + (size_t)(n0 + r_b) * DMOD + kk + kc;
    *(uint4*)&Bs[r_b * 40 + kc] = *(const uint4*)gb;
    *(uint4*)&Bs[(r_b + 64) * 40 + kc] = *(const uint4*)(gb + (size_t)64 * DMOD);
    __syncthreads();
    f16x8 af[4], bfr[4];
    int ka = quad * 8;
#pragma unroll
    for (int i = 0; i < 4; i++) {
      int mrow = wm + i * 16 + l15;
      uint4 fa;
      fa.x = Ta[(quad * 4 + 0) * 132 + mrow];
      fa.y = Ta[(quad * 4 + 1) * 132 + mrow];
      fa.z = Ta[(quad * 4 + 2) * 132 + mrow];
      fa.w = Ta[(quad * 4 + 3) * 132 + mrow];
      af[i] = *(f16x8*)&fa;
    }
#pragma unroll
    for (int j = 0; j < 4; j++)
      bfr[j] = *(const f16x8*)&Bs[(wn + j * 16 + l15) * 40 + ka];
#pragma unroll
    for (int i = 0; i < 4; i++)
#pragma unroll
      for (int j = 0; j < 4; j++)
        acc[i][j] = __builtin_amdgcn_mfma_f32_16x16x32_f16(af[i], bfr[j], acc[i][j], 0, 0, 0);
  }

  float bv[4];
#pragma unroll
  for (int j = 0; j < 4; j++) bv[j] = bias[n0 + wn + j * 16 + l15];
  // fp32 epilogue in two 64-row passes through LDS (64 x 132 floats = 33792 B)
  float* Cf = (float*)smem;
#pragma unroll
  for (int half = 0; half < 2; half++) {
    __syncthreads();
    if ((wave >> 1) == half) {
#pragma unroll
      for (int i = 0; i < 4; i++) {
#pragma unroll
        for (int j = 0; j < 4; j++) {
          int mlocal = i * 16 + quad * 4;
          int nl = wn + j * 16 + l15;
#pragma unroll
          for (int r = 0; r < 4; r++)
            Cf[(mlocal + r) * 132 + nl] = acc[i][j][r] + bv[j];
        }
      }
    }
    __syncthreads();
#pragma unroll
    for (int it = 0; it < 8; it++) {
      int row = (tid >> 5) + it * 8;
      int col = (tid & 31) * 4;
      float4 v = *(const float4*)&Cf[row * 132 + col];
      *(float4*)(out + (size_t)b * LSEQ * DMOD +
                 (size_t)(m0 + half * 64 + row) * DMOD + n0 + col) = v;
    }
  }
}

// ---------------- per-channel FFT corr + top-16 + softmax --------------------
// Radix-16 Stockham (3 stages), one 32KB in-place LDS buffer, XOR bank swizzle.
// Stockham radix-R stage (matches proven radix-2 convention):
//   j = idx/m, k = idx%m:
//   dst[R*j*m + k + u*m] = (sum_r src[idx + r*N/R] * W_R^{ur}) * W_N^{u*j*m}
#define SWZ(t) ((t) ^ (((t) >> 4) & 15))

template <bool INV>
__device__ __forceinline__ void dft16(float2* z) {
  const float SQ = 0.70710678118654752440f;
  const float C1 = 0.92387953251128675613f;
  const float S1 = 0.38268343236508977173f;
  const float sg = INV ? 1.0f : -1.0f;
  // len=2
#pragma unroll
  for (int i = 0; i < 16; i += 2) {
    float2 a = z[i], b = z[i + 1];
    z[i] = make_float2(a.x + b.x, a.y + b.y);
    z[i + 1] = make_float2(a.x - b.x, a.y - b.y);
  }
  // len=4
  {
    const float wre[2] = {1.f, 0.f};
    const float wim[2] = {0.f, sg};
#pragma unroll
    for (int g = 0; g < 16; g += 4)
#pragma unroll
      for (int p = 0; p < 2; p++) {
        float2 a = z[g + p], b = z[g + p + 2];
        float2 t = make_float2(b.x * wre[p] - b.y * wim[p],
                               b.x * wim[p] + b.y * wre[p]);
        z[g + p] = make_float2(a.x + t.x, a.y + t.y);
        z[g + p + 2] = make_float2(a.x - t.x, a.y - t.y);
      }
  }
  // len=8
  {
    const float wre[4] = {1.f, SQ, 0.f, -SQ};
    const float wim[4] = {0.f, sg * SQ, sg, sg * SQ};
#pragma unroll
    for (int g = 0; g < 16; g += 8)
#pragma unroll
      for (int p = 0; p < 4; p++) {
        float2 a = z[g + p], b = z[g + p + 4];
        float2 t = make_float2(b.x * wre[p] - b.y * wim[p],
                               b.x * wim[p] + b.y * wre[p]);
        z[g + p] = make_float2(a.x + t.x, a.y + t.y);
        z[g + p + 4] = make_float2(a.x - t.x, a.y - t.y);
      }
  }
  // len=16
  {
    const float wre[8] = {1.f, C1, SQ, S1, 0.f, -S1, -SQ, -C1};
    const float wim[8] = {0.f, sg * S1, sg * SQ, sg * C1, sg, sg * C1, sg * SQ, sg * S1};
#pragma unroll
    for (int p = 0; p < 8; p++) {
      float2 a = z[p], b = z[p + 8];
      float2 t = make_float2(b.x * wre[p] - b.y * wim[p],
                             b.x * wim[p] + b.y * wre[p]);
      z[p] = make_float2(a.x + t.x, a.y + t.y);
      z[p + 8] = make_float2(a.x - t.x, a.y - t.y);
    }
  }
}

// waves_per_eu(4,4): LDS (35 KB) caps us at 4 blocks/CU = 4 waves/EU anyway.
// Pinning min=max=4 gives the allocator the full 128-VGPR budget so the
// z[16] working set stays in registers (R1 spilled ~134 B/thread at 64 VGPR).
__global__ __launch_bounds__(256)
__attribute__((amdgpu_waves_per_eu(4, 4)))
void fft_corr_topk_k(const u16* __restrict__ Qt,
                     const u16* __restrict__ Kt,
                     const float2* __restrict__ tw,
                     float* __restrict__ topw,
                     int* __restrict__ topd) {
  __shared__ float2 buf[4096];  // 32 KB, XOR-swizzled complex buffer
  __shared__ float candv[256];
  __shared__ int candi[256];
  __shared__ float tvs[TOPK];
  __shared__ int tds[TOPK];
  __shared__ int winner;
  int ch = blockIdx.x;
  int tid = threadIdx.x;
  const u16* qrow = Qt + (size_t)ch * LSEQ;
  const u16* krow = Kt + (size_t)ch * LSEQ;
  const int rev[16] = {0, 8, 4, 12, 2, 10, 6, 14, 1, 9, 5, 13, 3, 11, 7, 15};
  float2 z[16];

  // ---- forward stage 1 (m=1): global -> regs -> DFT16 -> twiddle -> LDS
#pragma unroll
  for (int r = 0; r < 16; r++) {
    int t = tid + 256 * r;
    z[rev[r]] = make_float2(h2f(qrow[t]), h2f(krow[t]));
  }
  dft16<false>(z);
#pragma unroll
  for (int u = 0; u < 16; u++) {
    float2 w = tw[(u * tid) & 4095];
    buf[SWZ(16 * tid + u)] = cmul(z[u], w);
  }
  __syncthreads();

  // ---- forward stage 2 (m=16)
  {
    int k16 = tid & 15, j = tid >> 4;
#pragma unroll
    for (int r = 0; r < 16; r++) z[rev[r]] = buf[SWZ(tid + 256 * r)];
    __syncthreads();
    dft16<false>(z);
#pragma unroll
    for (int u = 0; u < 16; u++) {
      float2 w = tw[(u * j * 16) & 4095];
      buf[SWZ(256 * j + k16 + 16 * u)] = cmul(z[u], w);
    }
  }
  __syncthreads();

  // ---- forward stage 3 (m=256, no twiddle): leaves Z[t] in buf
#pragma unroll
  for (int r = 0; r < 16; r++) z[rev[r]] = buf[SWZ(tid + 256 * r)];
  __syncthreads();
  dft16<false>(z);
#pragma unroll
  for (int u = 0; u < 16; u++) buf[SWZ(tid + 256 * u)] = z[u];
  __syncthreads();

  // ---- pointwise spectrum split + inverse stage 1 (m=1), fused
#pragma unroll
  for (int r = 0; r < 16; r++) {
    int t = tid + 256 * r;
    float2 zf = buf[SWZ(t)];
    float2 zn = buf[SWZ((4096 - t) & 4095)];
    float ax = zf.x + zn.x, ay = zf.y - zn.y;  // a = zf + conj(zn)
    float dx = zf.x - zn.x, dy = zf.y + zn.y;  // d = zf - conj(zn)
    float px = ax * dx + ay * dy;              // Re(a*conj(d))
    float py = ay * dx - ax * dy;              // Im(a*conj(d))
    z[rev[r]] = make_float2(-0.25f * py, 0.25f * px);  // (i/4)*a*conj(d)
  }
  __syncthreads();
  dft16<true>(z);
#pragma unroll
  for (int u = 0; u < 16; u++) {
    float2 w = tw[(u * tid) & 4095];
    buf[SWZ(16 * tid + u)] = cmul_conj(z[u], w);
  }
  __syncthreads();

  // ---- inverse stage 2 (m=16)
  {
    int k16 = tid & 15, j = tid >> 4;
#pragma unroll
    for (int r = 0; r < 16; r++) z[rev[r]] = buf[SWZ(tid + 256 * r)];
    __syncthreads();
    dft16<true>(z);
#pragma unroll
    for (int u = 0; u < 16; u++) {
      float2 w = tw[(u * j * 16) & 4095];
      buf[SWZ(256 * j + k16 + 16 * u)] = cmul_conj(z[u], w);
    }
  }
  __syncthreads();

  // ---- inverse stage 3 (m=256): corr values stay in registers
#pragma unroll
  for (int r = 0; r < 16; r++) z[rev[r]] = buf[SWZ(tid + 256 * r)];
  dft16<true>(z);
  float vals[16];  // vals[u] = 4096*corr[tid + 256*u]
#pragma unroll
  for (int u = 0; u < 16; u++) vals[u] = z[u].x;

  // ---- top-16 via cached per-thread local max (ties -> smaller t)
  const float NEGINF = -__builtin_inff();
  {
    float bvv = vals[0];
    int bu = 0;
#pragma unroll
    for (int u = 1; u < 16; u++)
      if (vals[u] > bvv) { bvv = vals[u]; bu = u; }
    candv[tid] = bvv;
    candi[tid] = tid + (bu << 8);
  }
  for (int r = 0; r < TOPK; r++) {
    __syncthreads();
    if (tid < 64) {
      float v0 = candv[tid];
      int i0 = candi[tid];
#pragma unroll
      for (int s2 = 1; s2 < 4; s2++) {
        float v1 = candv[tid + 64 * s2];
        int i1 = candi[tid + 64 * s2];
        if (v1 > v0 || (v1 == v0 && i1 < i0)) { v0 = v1; i0 = i1; }
      }
#pragma unroll
      for (int off = 32; off > 0; off >>= 1) {
        float ov = __shfl_down(v0, off);
        int oi = __shfl_down(i0, off);
        if (ov > v0 || (ov == v0 && oi < i0)) { v0 = ov; i0 = oi; }
      }
      if (tid == 0) { tvs[r] = v0; tds[r] = i0; winner = i0; }
    }
    __syncthreads();
    int wn = winner;
    if ((wn & 255) == tid) {
      int ku = wn >> 8;
#pragma unroll
      for (int u = 0; u < 16; u++)
        if (u == ku) vals[u] = NEGINF;  // static index keeps vals in VGPRs
      float bvv = vals[0];
      int bu = 0;
#pragma unroll
      for (int u = 1; u < 16; u++)
        if (vals[u] > bvv) { bvv = vals[u]; bu = u; }
      candv[tid] = bvv;
      candi[tid] = tid + (bu << 8);
    }
  }
  __syncthreads();
  if (tid == 0) {
    float mx = tvs[0];
    float e[TOPK];
    float s = 0.f;
#pragma unroll
    for (int k2 = 0; k2 < TOPK; k2++) {
      e[k2] = __expf((tvs[k2] - mx) * (1.0f / 4096.0f));  // /4096 undoes unnorm. iFFT
      s += e[k2];
    }
    float inv = 1.0f / s;
#pragma unroll
    for (int k2 = 0; k2 < TOPK; k2++) {
      topw[(size_t)ch * TOPK + k2] = e[k2] * inv;
      topd[(size_t)ch * TOPK + k2] = tds[k2];
    }
  }
}

// ---------------- delay aggregation: agg[c,t] = sum_k w_k * v[c,(t+d_k)%L] --
__global__ __launch_bounds__(256) void aggregate_k(const u16* __restrict__ Vt,
                                                   const float* __restrict__ topw,
                                                   const int* __restrict__ topd,
                                                   u16* __restrict__ agg) {
  __shared__ u16 vrow[4096];
  __shared__ float w_s[TOPK];
  __shared__ int d_s[TOPK];
  int ch = blockIdx.x, tid = threadIdx.x;
  const u16* src = Vt + (size_t)ch * LSEQ;
#pragma unroll
  for (int p = 0; p < 16; p++) vrow[tid + p * 256] = src[tid + p * 256];
  if (tid < TOPK) {
    w_s[tid] = topw[(size_t)ch * TOPK + tid];
    d_s[tid] = topd[(size_t)ch * TOPK + tid];
  }
  __syncthreads();
#pragma unroll
  for (int p = 0; p < 16; p++) {
    int t = tid + p * 256;
    float s = 0.f;
#pragma unroll
    for (int k = 0; k < TOPK; k++)
      s += w_s[k] * h2f(vrow[(t + d_s[k]) & 4095]);
    agg[(size_t)ch * LSEQ + t] = f2h(s);
  }
}

extern "C" void kernel_launch(void* const* d_in, const int* in_sizes, int n_in,
                              void* d_out, int out_size, void* d_ws, size_t ws_size,
                              hipStream_t stream) {
  (void)in_sizes; (void)n_in; (void)out_size; (void)ws_size;
  const float* queries = (const float*)d_in[0];
  const float* keys    = (const float*)d_in[1];
  const float* values  = (const float*)d_in[2];
  const float* Wq = (const float*)d_in[3];
  const float* bq = (const float*)d_in[4];
  const float* Wk = (const float*)d_in[5];
  const float* bk = (const float*)d_in[6];
  const float* Wv = (const float*)d_in[7];
  const float* bv = (const float*)d_in[8];
  const float* Wo = (const float*)d_in[9];
  const float* bo = (const float*)d_in[10];

  // ws layout, total ~73.1 MB (R3-proven):
  //   ws0 @ 0       : 64 MB big buffer (Qt fp16, then agg fp16)
  //   Wt's @ 64 MB  : 4 x 2 MB transposed fp16 weights
  //   tw   @ 72 MB  : 32 KB twiddles (4096 entries)
  //   topw @ 72M+64K: 512 KB, topd @ +512 KB
  char* ws = (char*)d_ws;
  u16* ws0 = (u16*)ws;
  u16* Wqt = (u16*)(ws + (64ull << 20));
  u16* Wkt = Wqt + 1024 * 1024;
  u16* Wvt = Wkt + 1024 * 1024;
  u16* Wot = Wvt + 1024 * 1024;
  float2* tw = (float2*)(ws + (72ull << 20));
  float* topw = (float*)(ws + (72ull << 20) + (64ull << 10));
  int* topd = (int*)(ws + (72ull << 20) + (64ull << 10) + (512ull << 10));

  u16* Qt = ws0;            // fp16 [B][1024][4096]
  u16* Kt = (u16*)d_out;    // fp16 K-proj in d_out (d_out is 128 MB fp32)
  u16* Vt = (u16*)d_out;    // then fp16 V-proj in d_out
  u16* agg = ws0;           // fp16 channel-major aggregation (Qt dead)

  twiddle_k<<<dim3(16), dim3(256), 0, stream>>>(tw);
  transpose_w_k<<<dim3(16, 16), dim3(256), 0, stream>>>(Wq, Wqt, 1024, 1024);
  transpose_w_k<<<dim3(16, 16), dim3(256), 0, stream>>>(Wk, Wkt, 1024, 1024);
  transpose_w_k<<<dim3(16, 16), dim3(256), 0, stream>>>(Wv, Wvt, 1024, 1024);
  transpose_w_k<<<dim3(16, 16), dim3(256), 0, stream>>>(Wo, Wot, 1024, 1024);
  dim3 gg(8, 256);
  gemm_proj_k<<<gg, dim3(256), 0, stream>>>(queries, Wqt, bq, Qt, 1024);
  gemm_proj_k<<<gg, dim3(256), 0, stream>>>(keys, Wkt, bk, Kt, 1024);
  fft_corr_topk_k<<<dim3(NCH), dim3(256), 0, stream>>>(Qt, Kt, tw, topw, topd);
  gemm_proj_k<<<gg, dim3(256), 0, stream>>>(values, Wvt, bv, Vt, 1024);
  aggregate_k<<<dim3(NCH), dim3(256), 0, stream>>>(Vt, topw, topd, agg);
  gemm_tA_k<<<dim3(8, 32, 8), dim3(256), 0, stream>>>(agg, Wot, bo, (float*)d_out);
}

// Round 3
// 1438.577 us; speedup vs baseline: 1.1037x; 1.0144x over previous
//
#include <hip/hip_runtime.h>
#include <hip/hip_bf16.h>
#include <string.h>

#define NB 8
#define LSEQ 4096
#define DMOD 1024
#define NCH (NB * DMOD)   // 8192 channels (b, c=h*128+dk)
#define TOPK 16

typedef unsigned short u16;
typedef unsigned int u32;
typedef __attribute__((ext_vector_type(4))) float f32x4;
typedef __attribute__((ext_vector_type(8))) _Float16 f16x8;

__device__ __forceinline__ float h2f(u16 u) {
  _Float16 h;
  __builtin_memcpy(&h, &u, 2);
  return (float)h;
}
__device__ __forceinline__ u16 f2h(float f) {
  _Float16 h = (_Float16)f;  // v_cvt_f16_f32, RNE
  u16 u;
  __builtin_memcpy(&u, &h, 2);
  return u;
}
__device__ __forceinline__ u32 pk2(float a, float b) {
  return (u32)f2h(a) | ((u32)f2h(b) << 16);
}
__device__ __forceinline__ float2 cmul(float2 a, float2 b) {
  return make_float2(a.x * b.x - a.y * b.y, a.x * b.y + a.y * b.x);
}
__device__ __forceinline__ float2 cmul_conj(float2 a, float2 b) {  // a * conj(b)
  return make_float2(a.x * b.x + a.y * b.y, a.y * b.x - a.x * b.y);
}

// ---------------- twiddle table: T[x] = exp(-2*pi*i*x/4096), x<4096 ----------
__global__ __launch_bounds__(256) void twiddle_k(float2* tw) {
  int i = blockIdx.x * 256 + threadIdx.x;
  if (i < 4096) {
    float ang = -2.0f * 3.14159265358979323846f * (float)i / 4096.0f;
    tw[i] = make_float2(cosf(ang), sinf(ang));
  }
}

// -------- weight transpose + fp16 downcast: dst[c][r] = fp16(src[r][c]) -----
__global__ __launch_bounds__(256) void transpose_w_k(const float* __restrict__ src,
                                                     u16* __restrict__ dst,
                                                     int R, int C) {
  __shared__ u16 tile[64][66];
  int c0 = blockIdx.x * 64, r0 = blockIdx.y * 64;
  int tx = threadIdx.x & 63, ty = threadIdx.x >> 6;
#pragma unroll
  for (int i = 0; i < 16; i++) {
    int r = ty + i * 4;
    tile[r][tx] = f2h(src[(size_t)(r0 + r) * C + c0 + tx]);
  }
  __syncthreads();
#pragma unroll
  for (int i = 0; i < 16; i++) {
    int cc = ty + i * 4;
    dst[(size_t)(c0 + cc) * R + r0 + tx] = tile[tx][cc];
  }
}

// ------- proj GEMM: out[b][n][t] = fp16( sum_k A[m][k]*Btw[n][k] + bias[n] )
// A fp32 [M=32768][K=1024] (m = b*4096+t), Btw fp16 [N=1024][K], bias fp32.
__global__ __launch_bounds__(256) void gemm_proj_k(const float* __restrict__ A,
                                                   const u16* __restrict__ Btw,
                                                   const float* __restrict__ bias,
                                                   u16* __restrict__ out,
                                                   int K) {
  __shared__ __align__(16) u16 smem[17408];  // staging (2x128x40) / C-tile (128x136)
  u16* As = smem;
  u16* Bs = smem + 5120;
  int tid = threadIdx.x;
  int lane = tid & 63, wave = tid >> 6;
  int quad = lane >> 4, l15 = lane & 15;
  int m0 = blockIdx.y * 128, n0 = blockIdx.x * 128;
  int wm = (wave >> 1) * 64, wn = (wave & 1) * 64;
  int r_a = tid >> 2, kc = (tid & 3) * 8;

  f32x4 acc[4][4];
#pragma unroll
  for (int i = 0; i < 4; i++)
#pragma unroll
    for (int j = 0; j < 4; j++)
      acc[i][j] = (f32x4){0.f, 0.f, 0.f, 0.f};

  for (int kk = 0; kk < K; kk += 32) {
    __syncthreads();
    const float* ga0 = A + (size_t)(m0 + r_a) * K + kk + kc;
    const float* ga1 = ga0 + (size_t)64 * K;
    float4 x0 = *(const float4*)ga0;
    float4 x1 = *(const float4*)(ga0 + 4);
    float4 y0 = *(const float4*)ga1;
    float4 y1 = *(const float4*)(ga1 + 4);
    uint4 wa, wb;
    wa.x = pk2(x0.x, x0.y); wa.y = pk2(x0.z, x0.w);
    wa.z = pk2(x1.x, x1.y); wa.w = pk2(x1.z, x1.w);
    wb.x = pk2(y0.x, y0.y); wb.y = pk2(y0.z, y0.w);
    wb.z = pk2(y1.x, y1.y); wb.w = pk2(y1.z, y1.w);
    *(uint4*)&As[r_a * 40 + kc] = wa;
    *(uint4*)&As[(r_a + 64) * 40 + kc] = wb;
    const u16* gb = Btw + (size_t)(n0 + r_a) * K + kk + kc;
    *(uint4*)&Bs[r_a * 40 + kc] = *(const uint4*)gb;
    *(uint4*)&Bs[(r_a + 64) * 40 + kc] = *(const uint4*)(gb + (size_t)64 * K);
    __syncthreads();
    f16x8 af[4], bfr[4];
    int ka = quad * 8;
#pragma unroll
    for (int i = 0; i < 4; i++)
      af[i] = *(const f16x8*)&As[(wm + i * 16 + l15) * 40 + ka];
#pragma unroll
    for (int j = 0; j < 4; j++)
      bfr[j] = *(const f16x8*)&Bs[(wn + j * 16 + l15) * 40 + ka];
#pragma unroll
    for (int i = 0; i < 4; i++)
#pragma unroll
      for (int j = 0; j < 4; j++)
        acc[i][j] = __builtin_amdgcn_mfma_f32_16x16x32_f16(af[i], bfr[j], acc[i][j], 0, 0, 0);
  }

  __syncthreads();
  float bv[4];
#pragma unroll
  for (int j = 0; j < 4; j++) bv[j] = bias[n0 + wn + j * 16 + l15];
  u16* Ct = smem;  // [n 128][m 136] transposed C-tile
#pragma unroll
  for (int i = 0; i < 4; i++) {
#pragma unroll
    for (int j = 0; j < 4; j++) {
      int ml = wm + i * 16 + quad * 4;
      int nl = wn + j * 16 + l15;
      unsigned long long pkv = 0;
#pragma unroll
      for (int r = 0; r < 4; r++)
        pkv |= ((unsigned long long)f2h(acc[i][j][r] + bv[j])) << (16 * r);
      *(unsigned long long*)&Ct[nl * 136 + ml] = pkv;
    }
  }
  __syncthreads();
  int b_ = m0 >> 12, t0 = m0 & 4095;
#pragma unroll
  for (int it = 0; it < 8; it++) {
    int row = (tid >> 4) + it * 16;
    int col = (tid & 15) * 8;
    uint4 v = *(const uint4*)&Ct[row * 136 + col];
    *(uint4*)(out + (size_t)b_ * DMOD * LSEQ + (size_t)(n0 + row) * LSEQ + t0 + col) = v;
  }
}

// ------- final GEMM: out[b][t][n] = fp32( sum_c Acm[b][c][t]*Wot[n][c] ) + bo
// Acm fp16 channel-major [B][1024][4096]; A transposed during staging.
__global__ __launch_bounds__(256) void gemm_tA_k(const u16* __restrict__ Acm,
                                                 const u16* __restrict__ Wot,
                                                 const float* __restrict__ bias,
                                                 float* __restrict__ out) {
  __shared__ __align__(16) u16 smem[17408];
  u32* Ta = (u32*)smem;            // 16 c-pairs x 132 dwords = 2112 dw (8448 B)
  u16* Bs = smem + 4224;           // 128 x 40
  int tid = threadIdx.x;
  int lane = tid & 63, wave = tid >> 6;
  int quad = lane >> 4, l15 = lane & 15;
  int b = blockIdx.z;
  int m0 = blockIdx.y * 128, n0 = blockIdx.x * 128;
  int wm = (wave >> 1) * 64, wn = (wave & 1) * 64;
  int cp = tid >> 4, t0s = (tid & 15) * 8;   // A staging: c-pair, t-offset
  int r_b = tid >> 2, kc = (tid & 3) * 8;    // B staging
  const u16* Ab = Acm + (size_t)b * DMOD * LSEQ;

  f32x4 acc[4][4];
#pragma unroll
  for (int i = 0; i < 4; i++)
#pragma unroll
    for (int j = 0; j < 4; j++)
      acc[i][j] = (f32x4){0.f, 0.f, 0.f, 0.f};

  for (int kk = 0; kk < DMOD; kk += 32) {
    __syncthreads();
    const u16* ga = Ab + (size_t)(kk + 2 * cp) * LSEQ + m0 + t0s;
    uint4 v0 = *(const uint4*)ga;
    uint4 v1 = *(const uint4*)(ga + LSEQ);
    int tb = cp * 132 + t0s;
    uint4 w0, w1;
    w0.x = (v0.x & 0xffffu) | (v1.x << 16);
    w0.y = (v0.x >> 16) | (v1.x & 0xffff0000u);
    w0.z = (v0.y & 0xffffu) | (v1.y << 16);
    w0.w = (v0.y >> 16) | (v1.y & 0xffff0000u);
    w1.x = (v0.z & 0xffffu) | (v1.z << 16);
    w1.y = (v0.z >> 16) | (v1.z & 0xffff0000u);
    w1.z = (v0.w & 0xffffu) | (v1.w << 16);
    w1.w = (v0.w >> 16) | (v1.w & 0xffff0000u);
    *(uint4*)&Ta[tb] = w0;
    *(uint4*)&Ta[tb + 4] = w1;
    const u16* gb = Wot + (size_t)(n0 + r_b) * DMOD + kk + kc;
    *(uint4*)&Bs[r_b * 40 + kc] = *(const uint4*)gb;
    *(uint4*)&Bs[(r_b + 64) * 40 + kc] = *(const uint4*)(gb + (size_t)64 * DMOD);
    __syncthreads();
    f16x8 af[4], bfr[4];
    int ka = quad * 8;
#pragma unroll
    for (int i = 0; i < 4; i++) {
      int mrow = wm + i * 16 + l15;
      uint4 fa;
      fa.x = Ta[(quad * 4 + 0) * 132 + mrow];
      fa.y = Ta[(quad * 4 + 1) * 132 + mrow];
      fa.z = Ta[(quad * 4 + 2) * 132 + mrow];
      fa.w = Ta[(quad * 4 + 3) * 132 + mrow];
      af[i] = *(f16x8*)&fa;
    }
#pragma unroll
    for (int j = 0; j < 4; j++)
      bfr[j] = *(const f16x8*)&Bs[(wn + j * 16 + l15) * 40 + ka];
#pragma unroll
    for (int i = 0; i < 4; i++)
#pragma unroll
      for (int j = 0; j < 4; j++)
        acc[i][j] = __builtin_amdgcn_mfma_f32_16x16x32_f16(af[i], bfr[j], acc[i][j], 0, 0, 0);
  }

  float bv[4];
#pragma unroll
  for (int j = 0; j < 4; j++) bv[j] = bias[n0 + wn + j * 16 + l15];
  // fp32 epilogue in two 64-row passes through LDS (64 x 132 floats = 33792 B)
  float* Cf = (float*)smem;
#pragma unroll
  for (int half = 0; half < 2; half++) {
    __syncthreads();
    if ((wave >> 1) == half) {
#pragma unroll
      for (int i = 0; i < 4; i++) {
#pragma unroll
        for (int j = 0; j < 4; j++) {
          int mlocal = i * 16 + quad * 4;
          int nl = wn + j * 16 + l15;
#pragma unroll
          for (int r = 0; r < 4; r++)
            Cf[(mlocal + r) * 132 + nl] = acc[i][j][r] + bv[j];
        }
      }
    }
    __syncthreads();
#pragma unroll
    for (int it = 0; it < 8; it++) {
      int row = (tid >> 5) + it * 8;
      int col = (tid & 31) * 4;
      float4 v = *(const float4*)&Cf[row * 132 + col];
      *(float4*)(out + (size_t)b * LSEQ * DMOD +
                 (size_t)(m0 + half * 64 + row) * DMOD + n0 + col) = v;
    }
  }
}

// ---------------- per-channel FFT corr + top-16 + softmax --------------------
// Radix-16 Stockham (3 stages), one 32KB in-place LDS buffer, XOR bank swizzle.
// R3: z[]/vals[] arrays replaced by NAMED registers via macros. SROA runs
// before loop unrolling, so any loop-var index (even #pragma unroll'd) demotes
// the array to scratch (rule #20) -- R1/R2 showed 281 MB of HBM scratch
// write-back (137 B/thread = sizeof z[16]). All indices below are literal.
#define SWZ(t) ((t) ^ (((t) >> 4) & 15))

#define FOREACH16(M) M(0) M(1) M(2) M(3) M(4) M(5) M(6) M(7) \
                     M(8) M(9) M(10) M(11) M(12) M(13) M(14) M(15)
// M(r, k): logical input r lands in z##k (k = bitrev4(r)); dft then yields
// natural-order outputs in z0..z15.
#define BITREV16(M) M(0,0) M(1,8) M(2,4) M(3,12) M(4,2) M(5,10) M(6,6) M(7,14) \
                    M(8,1) M(9,9) M(10,5) M(11,13) M(12,3) M(13,11) M(14,7) M(15,15)

#define BF(a, b) { float tx = (b).x, ty = (b).y; \
                   (b).x = (a).x - tx; (b).y = (a).y - ty; \
                   (a).x += tx; (a).y += ty; }
#define BFW(a, b, wr, wi) { float tx = (b).x*(wr) - (b).y*(wi); \
                            float ty = (b).x*(wi) + (b).y*(wr); \
                            (b).x = (a).x - tx; (b).y = (a).y - ty; \
                            (a).x += tx; (a).y += ty; }

#define FFT_SQ 0.70710678118654752440f
#define FFT_C1 0.92387953251128675613f
#define FFT_S1 0.38268343236508977173f

// SGc = -1.f forward, +1.f inverse (matches prior dft16<INV> op-for-op)
#define DFT16(SGc) \
  BF(z0,z1) BF(z2,z3) BF(z4,z5) BF(z6,z7) BF(z8,z9) BF(z10,z11) BF(z12,z13) BF(z14,z15) \
  BF(z0,z2) BFW(z1,z3,0.f,(SGc)) BF(z4,z6) BFW(z5,z7,0.f,(SGc)) \
  BF(z8,z10) BFW(z9,z11,0.f,(SGc)) BF(z12,z14) BFW(z13,z15,0.f,(SGc)) \
  BF(z0,z4) BFW(z1,z5,FFT_SQ,(SGc)*FFT_SQ) BFW(z2,z6,0.f,(SGc)) BFW(z3,z7,-FFT_SQ,(SGc)*FFT_SQ) \
  BF(z8,z12) BFW(z9,z13,FFT_SQ,(SGc)*FFT_SQ) BFW(z10,z14,0.f,(SGc)) BFW(z11,z15,-FFT_SQ,(SGc)*FFT_SQ) \
  BF(z0,z8) BFW(z1,z9,FFT_C1,(SGc)*FFT_S1) BFW(z2,z10,FFT_SQ,(SGc)*FFT_SQ) BFW(z3,z11,FFT_S1,(SGc)*FFT_C1) \
  BFW(z4,z12,0.f,(SGc)) BFW(z5,z13,-FFT_S1,(SGc)*FFT_C1) BFW(z6,z14,-FFT_SQ,(SGc)*FFT_SQ) BFW(z7,z15,-FFT_C1,(SGc)*FFT_S1)

__global__ __launch_bounds__(256, 4)
void fft_corr_topk_k(const u16* __restrict__ Qt,
                     const u16* __restrict__ Kt,
                     const float2* __restrict__ tw,
                     float* __restrict__ topw,
                     int* __restrict__ topd) {
  __shared__ float2 buf[4096];  // 32 KB, XOR-swizzled complex buffer
  __shared__ float candv[256];
  __shared__ int candi[256];
  __shared__ float tvs[TOPK];
  __shared__ int tds[TOPK];
  __shared__ int winner;
  int ch = blockIdx.x;
  int tid = threadIdx.x;
  const u16* qrow = Qt + (size_t)ch * LSEQ;
  const u16* krow = Kt + (size_t)ch * LSEQ;
  const int jj = tid >> 4, k16 = tid & 15;

#define DECLZ(u) float2 z##u;
  FOREACH16(DECLZ)

  // ---- forward stage 1 (m=1): global -> regs -> DFT16 -> twiddle -> LDS
#define LD1(r, k) { int t = tid + 256 * (r); \
                    z##k = make_float2(h2f(qrow[t]), h2f(krow[t])); }
  BITREV16(LD1)
  DFT16(-1.f)
#define ST1(u) { float2 w = tw[((u) * tid) & 4095]; \
                 buf[SWZ(16 * tid + (u))] = cmul(z##u, w); }
  FOREACH16(ST1)
  __syncthreads();

  // ---- forward stage 2 (m=16)
#define LD2(r, k) z##k = buf[SWZ(tid + 256 * (r))];
  BITREV16(LD2)
  __syncthreads();
  DFT16(-1.f)
#define ST2F(u) { float2 w = tw[((u) * jj * 16) & 4095]; \
                  buf[SWZ(256 * jj + k16 + 16 * (u))] = cmul(z##u, w); }
  FOREACH16(ST2F)
  __syncthreads();

  // ---- forward stage 3 (m=256, no twiddle): leaves Z[t] in buf
  BITREV16(LD2)
  __syncthreads();
  DFT16(-1.f)
#define ST3(u) buf[SWZ(tid + 256 * (u))] = z##u;
  FOREACH16(ST3)
  __syncthreads();

  // ---- pointwise spectrum split + inverse stage 1 (m=1), fused
#define LDP(r, k) { int t = tid + 256 * (r); \
                    float2 zf = buf[SWZ(t)]; \
                    float2 zn = buf[SWZ((4096 - t) & 4095)]; \
                    float ax = zf.x + zn.x, ay = zf.y - zn.y; \
                    float dx = zf.x - zn.x, dy = zf.y + zn.y; \
                    float px = ax * dx + ay * dy; \
                    float py = ay * dx - ax * dy; \
                    z##k = make_float2(-0.25f * py, 0.25f * px); }
  BITREV16(LDP)
  __syncthreads();
  DFT16(1.f)
#define ST1I(u) { float2 w = tw[((u) * tid) & 4095]; \
                  buf[SWZ(16 * tid + (u))] = cmul_conj(z##u, w); }
  FOREACH16(ST1I)
  __syncthreads();

  // ---- inverse stage 2 (m=16)
  BITREV16(LD2)
  __syncthreads();
  DFT16(1.f)
#define ST2I(u) { float2 w = tw[((u) * jj * 16) & 4095]; \
                  buf[SWZ(256 * jj + k16 + 16 * (u))] = cmul_conj(z##u, w); }
  FOREACH16(ST2I)
  __syncthreads();

  // ---- inverse stage 3 (m=256): corr values stay in registers
  BITREV16(LD2)
  DFT16(1.f)
#define DECLV(u) float v##u = z##u.x;  // v##u = 4096*corr[tid + 256*u]
  FOREACH16(DECLV)

  // ---- top-16 via cached per-thread local max (ties -> smaller t)
  const float NEGINF = -__builtin_inff();
  {
    float bvv = v0;
    int bu = 0;
#define AMX(u) if (v##u > bvv) { bvv = v##u; bu = (u); }
    AMX(1) AMX(2) AMX(3) AMX(4) AMX(5) AMX(6) AMX(7)
    AMX(8) AMX(9) AMX(10) AMX(11) AMX(12) AMX(13) AMX(14) AMX(15)
    candv[tid] = bvv;
    candi[tid] = tid + (bu << 8);
  }
  for (int r = 0; r < TOPK; r++) {
    __syncthreads();
    if (tid < 64) {
      float v0r = candv[tid];
      int i0r = candi[tid];
#pragma unroll
      for (int s2 = 1; s2 < 4; s2++) {
        float v1r = candv[tid + 64 * s2];
        int i1r = candi[tid + 64 * s2];
        if (v1r > v0r || (v1r == v0r && i1r < i0r)) { v0r = v1r; i0r = i1r; }
      }
#pragma unroll
      for (int off = 32; off > 0; off >>= 1) {
        float ov = __shfl_down(v0r, off);
        int oi = __shfl_down(i0r, off);
        if (ov > v0r || (ov == v0r && oi < i0r)) { v0r = ov; i0r = oi; }
      }
      if (tid == 0) { tvs[r] = v0r; tds[r] = i0r; winner = i0r; }
    }
    __syncthreads();
    int wnr = winner;
    if ((wnr & 255) == tid) {
      int ku = wnr >> 8;
#define KILLV(u) if (ku == (u)) v##u = NEGINF;
      FOREACH16(KILLV)
      float bvv = v0;
      int bu = 0;
      AMX(1) AMX(2) AMX(3) AMX(4) AMX(5) AMX(6) AMX(7)
      AMX(8) AMX(9) AMX(10) AMX(11) AMX(12) AMX(13) AMX(14) AMX(15)
      candv[tid] = bvv;
      candi[tid] = tid + (bu << 8);
    }
  }
  __syncthreads();
  if (tid == 0) {
    float mx = tvs[0];
    float e[TOPK];
    float s = 0.f;
#pragma unroll
    for (int k2 = 0; k2 < TOPK; k2++) {
      e[k2] = __expf((tvs[k2] - mx) * (1.0f / 4096.0f));  // /4096 undoes unnorm. iFFT
      s += e[k2];
    }
    float inv = 1.0f / s;
#pragma unroll
    for (int k2 = 0; k2 < TOPK; k2++) {
      topw[(size_t)ch * TOPK + k2] = e[k2] * inv;
      topd[(size_t)ch * TOPK + k2] = tds[k2];
    }
  }
}

// ---------------- delay aggregation: agg[c,t] = sum_k w_k * v[c,(t+d_k)%L] --
__global__ __launch_bounds__(256) void aggregate_k(const u16* __restrict__ Vt,
                                                   const float* __restrict__ topw,
                                                   const int* __restrict__ topd,
                                                   u16* __restrict__ agg) {
  __shared__ u16 vrow[4096];
  __shared__ float w_s[TOPK];
  __shared__ int d_s[TOPK];
  int ch = blockIdx.x, tid = threadIdx.x;
  const u16* src = Vt + (size_t)ch * LSEQ;
#pragma unroll
  for (int p = 0; p < 16; p++) vrow[tid + p * 256] = src[tid + p * 256];
  if (tid < TOPK) {
    w_s[tid] = topw[(size_t)ch * TOPK + tid];
    d_s[tid] = topd[(size_t)ch * TOPK + tid];
  }
  __syncthreads();
#pragma unroll
  for (int p = 0; p < 16; p++) {
    int t = tid + p * 256;
    float s = 0.f;
#pragma unroll
    for (int k = 0; k < TOPK; k++)
      s += w_s[k] * h2f(vrow[(t + d_s[k]) & 4095]);
    agg[(size_t)ch * LSEQ + t] = f2h(s);
  }
}

extern "C" void kernel_launch(void* const* d_in, const int* in_sizes, int n_in,
                              void* d_out, int out_size, void* d_ws, size_t ws_size,
                              hipStream_t stream) {
  (void)in_sizes; (void)n_in; (void)out_size; (void)ws_size;
  const float* queries = (const float*)d_in[0];
  const float* keys    = (const float*)d_in[1];
  const float* values  = (const float*)d_in[2];
  const float* Wq = (const float*)d_in[3];
  const float* bq = (const float*)d_in[4];
  const float* Wk = (const float*)d_in[5];
  const float* bk = (const float*)d_in[6];
  const float* Wv = (const float*)d_in[7];
  const float* bv = (const float*)d_in[8];
  const float* Wo = (const float*)d_in[9];
  const float* bo = (const float*)d_in[10];

  // ws layout, total ~73.1 MB (R3-proven):
  //   ws0 @ 0       : 64 MB big buffer (Qt fp16, then agg fp16)
  //   Wt's @ 64 MB  : 4 x 2 MB transposed fp16 weights
  //   tw   @ 72 MB  : 32 KB twiddles (4096 entries)
  //   topw @ 72M+64K: 512 KB, topd @ +512 KB
  char* ws = (char*)d_ws;
  u16* ws0 = (u16*)ws;
  u16* Wqt = (u16*)(ws + (64ull << 20));
  u16* Wkt = Wqt + 1024 * 1024;
  u16* Wvt = Wkt + 1024 * 1024;
  u16* Wot = Wvt + 1024 * 1024;
  float2* tw = (float2*)(ws + (72ull << 20));
  float* topw = (float*)(ws + (72ull << 20) + (64ull << 10));
  int* topd = (int*)(ws + (72ull << 20) + (64ull << 10) + (512ull << 10));

  u16* Qt = ws0;            // fp16 [B][1024][4096]
  u16* Kt = (u16*)d_out;    // fp16 K-proj in d_out (d_out is 128 MB fp32)
  u16* Vt = (u16*)d_out;    // then fp16 V-proj in d_out
  u16* agg = ws0;           // fp16 channel-major aggregation (Qt dead)

  twiddle_k<<<dim3(16), dim3(256), 0, stream>>>(tw);
  transpose_w_k<<<dim3(16, 16), dim3(256), 0, stream>>>(Wq, Wqt, 1024, 1024);
  transpose_w_k<<<dim3(16, 16), dim3(256), 0, stream>>>(Wk, Wkt, 1024, 1024);
  transpose_w_k<<<dim3(16, 16), dim3(256), 0, stream>>>(Wv, Wvt, 1024, 1024);
  transpose_w_k<<<dim3(16, 16), dim3(256), 0, stream>>>(Wo, Wot, 1024, 1024);
  dim3 gg(8, 256);
  gemm_proj_k<<<gg, dim3(256), 0, stream>>>(queries, Wqt, bq, Qt, 1024);
  gemm_proj_k<<<gg, dim3(256), 0, stream>>>(keys, Wkt, bk, Kt, 1024);
  fft_corr_topk_k<<<dim3(NCH), dim3(256), 0, stream>>>(Qt, Kt, tw, topw, topd);
  gemm_proj_k<<<gg, dim3(256), 0, stream>>>(values, Wvt, bv, Vt, 1024);
  aggregate_k<<<dim3(NCH), dim3(256), 0, stream>>>(Vt, topw, topd, agg);
  gemm_tA_k<<<dim3(8, 32, 8), dim3(256), 0, stream>>>(agg, Wot, bo, (float*)d_out);
}